// Round 2
// baseline (1031.754 us; speedup 1.0000x reference)
//
#include <hip/hip_runtime.h>
#include <hip/hip_bf16.h>

// LSTMCell fused: g = hx @ W + b  (M=8192, K=2048, N=7*2048), then gate math.
// bf16 MFMA (16x16x32), f32 accumulate, f32 epilogue.
//
// Tiling: BM=256 rows x BN=32 gate-cols per workgroup, all 7 gates fused.
// 8 waves = 4(M) x 2(N); wave tile = 64 rows x 16 cols x 7 gates.
// R2: v_cvt_pk_bf16_f32 staging converts; conflict-free b64/b128 LDS writes.

#define B_SZ 8192
#define D_SZ 2048
#define H_SZ 2048
#define NG   7
#define NW   (NG * H_SZ)      // 14336
#define BM   256
#define BN   32
#define BK   32
#define NTH  512
#define LDP  40               // BK + 8 pad (bf16 elems); stride 80B = 5*16B
#define NKST (D_SZ / BK)      // 64

typedef __attribute__((ext_vector_type(8))) short bf16x8;
typedef __attribute__((ext_vector_type(4))) float f32x4;

__device__ __forceinline__ uint32_t cvtpk(float lo, float hi) {
    uint32_t r;
    asm("v_cvt_pk_bf16_f32 %0, %1, %2" : "=v"(r) : "v"(lo), "v"(hi));
    return r;  // lo16 = bf16(lo), hi16 = bf16(hi), RNE
}
__device__ __forceinline__ float sigmoidf_(float x) {
    return 1.0f / (1.0f + __expf(-x));
}
__device__ __forceinline__ float tanhf_(float x) {
    float ax = fabsf(x);
    float e = __expf(2.0f * ax);          // inf for big ax -> t=1, no NaN
    float t = 1.0f - 2.0f / (e + 1.0f);
    return copysignf(t, x);
}
__device__ __forceinline__ float softplusf_(float x) {
    return (x > 30.0f) ? x : __logf(1.0f + __expf(x));
}

__global__ __launch_bounds__(NTH, 2) void lstm_fused(
    const float* __restrict__ hx, const float* __restrict__ cx1,
    const float* __restrict__ cx2, const float* __restrict__ dt,
    const float* __restrict__ W, const float* __restrict__ bias,
    float* __restrict__ out)
{
    __shared__ ushort sA[BM * LDP];        // [row][k] bf16
    __shared__ ushort sB[NG * BN * LDP];   // [(g*32+n)][k] bf16 (k contiguous)

    const int tid = threadIdx.x;

    // XCD-chunked swizzle (nwg = 2048, divisible by 8)
    const int nwg = gridDim.x;
    const int cpx = nwg >> 3;
    const int b0  = blockIdx.x;
    const int swz = (b0 & 7) * cpx + (b0 >> 3);
    const int bx  = swz & 31;     // row-block; fast-varying within an XCD
    const int by  = swz >> 5;     // gate-col block
    const int gm0 = bx * BM;
    const int n0  = by * BN;

    const int lane = tid & 63;
    const int wid  = tid >> 6;
    const int wm   = wid >> 1;    // 0..3
    const int wn   = wid & 1;     // 0..1
    const int l15  = lane & 15;
    const int lg   = lane >> 4;   // 0..3

    // ---- A staging decomposition: 1024 chunks (256 rows x 4 k-octets), 2/thread
    const int ar0 = tid >> 2,          aq0 = tid & 3;          // chunk tid
    const int ar1 = (tid + 512) >> 2,  aq1 = tid & 3;          // chunk tid+512
    // ---- B staging decomposition: 448 units = 7g x 8kq x 8nq; thread -> 4 n
    const bool hasB = (tid < 448);                              // waves 0..6
    const int bg  = tid >> 6;          // gate
    const int bkq = (tid >> 3) & 7;    // k-quad (4 k)
    const int bnq = tid & 7;           // n-quad (4 n)

    f32x4 pa[4];       // 2 chunks x 8 floats
    f32x4 pb[4];       // 4 k-rows x 4 n floats

    auto issue_loads = [&](int K0) {
        {
            const float* p = hx + (size_t)(gm0 + ar0) * D_SZ + K0 + aq0 * 8;
            pa[0] = *(const f32x4*)(p);
            pa[1] = *(const f32x4*)(p + 4);
        }
        {
            const float* p = hx + (size_t)(gm0 + ar1) * D_SZ + K0 + aq1 * 8;
            pa[2] = *(const f32x4*)(p);
            pa[3] = *(const f32x4*)(p + 4);
        }
        if (hasB) {
            const float* p = W + (size_t)(K0 + bkq * 4) * NW + bg * H_SZ + n0 + bnq * 4;
            pb[0] = *(const f32x4*)(p);
            pb[1] = *(const f32x4*)(p + NW);
            pb[2] = *(const f32x4*)(p + 2 * NW);
            pb[3] = *(const f32x4*)(p + 3 * NW);
        }
    };

    auto store_lds = [&]() {
        {
            uint4 u;
            u.x = cvtpk(pa[0][0], pa[0][1]); u.y = cvtpk(pa[0][2], pa[0][3]);
            u.z = cvtpk(pa[1][0], pa[1][1]); u.w = cvtpk(pa[1][2], pa[1][3]);
            *(uint4*)(&sA[ar0 * LDP + aq0 * 8]) = u;
        }
        {
            uint4 u;
            u.x = cvtpk(pa[2][0], pa[2][1]); u.y = cvtpk(pa[2][2], pa[2][3]);
            u.z = cvtpk(pa[3][0], pa[3][1]); u.w = cvtpk(pa[3][2], pa[3][3]);
            *(uint4*)(&sA[ar1 * LDP + aq1 * 8]) = u;
        }
        if (hasB) {
            #pragma unroll
            for (int jj = 0; jj < 4; ++jj) {
                uint2 v;
                v.x = cvtpk(pb[0][jj], pb[1][jj]);   // k, k+1
                v.y = cvtpk(pb[2][jj], pb[3][jj]);   // k+2, k+3
                *(uint2*)(&sB[(bg * BN + bnq * 4 + jj) * LDP + bkq * 4]) = v;
            }
        }
    };

    // accumulators
    f32x4 acc[NG][4];
    #pragma unroll
    for (int g = 0; g < NG; ++g)
        #pragma unroll
        for (int mf = 0; mf < 4; ++mf)
            acc[g][mf] = (f32x4){0.f, 0.f, 0.f, 0.f};

    // LDS fragment read offsets (ushort index); 16B-aligned
    int aoff[4];
    #pragma unroll
    for (int mf = 0; mf < 4; ++mf)
        aoff[mf] = (wm * 64 + mf * 16 + l15) * LDP + lg * 8;
    int boff[NG];
    #pragma unroll
    for (int g = 0; g < NG; ++g)
        boff[g] = (g * BN + wn * 16 + l15) * LDP + lg * 8;

    issue_loads(0);
    for (int kk = 0; kk < NKST; ++kk) {
        store_lds();
        __syncthreads();
        if (kk + 1 < NKST) issue_loads((kk + 1) * BK);

        bf16x8 af[4];
        #pragma unroll
        for (int mf = 0; mf < 4; ++mf)
            af[mf] = *(const bf16x8*)(&sA[aoff[mf]]);
        #pragma unroll
        for (int g = 0; g < NG; ++g) {
            bf16x8 bfr = *(const bf16x8*)(&sB[boff[g]]);
            #pragma unroll
            for (int mf = 0; mf < 4; ++mf)
                acc[g][mf] = __builtin_amdgcn_mfma_f32_16x16x32_bf16(
                    af[mf], bfr, acc[g][mf], 0, 0, 0);
        }
        __syncthreads();
    }

    // epilogue: all 7 gate pre-activations live in registers
    const size_t BH = (size_t)B_SZ * H_SZ;
    const int j = n0 + wn * 16 + l15;
    float bj[NG];
    #pragma unroll
    for (int g = 0; g < NG; ++g) bj[g] = bias[g * H_SZ + j];

    #pragma unroll
    for (int mf = 0; mf < 4; ++mf) {
        #pragma unroll
        for (int r = 0; r < 4; ++r) {
            int row = gm0 + wm * 64 + mf * 16 + lg * 4 + r;
            float dtv = dt[row];
            float i1 = sigmoidf_(acc[0][mf][r] + bj[0]);
            float i2 = sigmoidf_(acc[1][mf][r] + bj[1]);
            float f1 = sigmoidf_(acc[2][mf][r] + bj[2]);
            float f2 = sigmoidf_(acc[3][mf][r] + bj[3]);
            float o  = sigmoidf_(acc[4][mf][r] + bj[4]);
            float z  = tanhf_(acc[5][mf][r] + bj[5]);
            float dec = softplusf_(acc[6][mf][r] + bj[6]);
            size_t idx = (size_t)row * H_SZ + j;
            float c1 = cx1[idx], c2 = cx2[idx];
            float cy1 = f1 * c1 + i1 * z;
            float cy2 = f2 * c2 + i2 * z;
            float ct  = cy2 + (cy1 - cy2) * __expf(-dec * dtv);
            float ht  = o * tanhf_(ct);
            out[idx]          = cy1;
            out[BH + idx]     = cy2;
            out[2 * BH + idx] = ht;
        }
    }
}

extern "C" void kernel_launch(void* const* d_in, const int* in_sizes, int n_in,
                              void* d_out, int out_size, void* d_ws, size_t ws_size,
                              hipStream_t stream) {
    const float* hx  = (const float*)d_in[0];
    const float* cx1 = (const float*)d_in[1];
    const float* cx2 = (const float*)d_in[2];
    // d_in[3] = tj (unused: t - tj == dt exactly)
    const float* dt  = (const float*)d_in[4];
    const float* W   = (const float*)d_in[5];
    const float* b   = (const float*)d_in[6];
    float* out = (float*)d_out;

    const int nblk = (B_SZ / BM) * (H_SZ / BN);   // 32 * 64 = 2048
    lstm_fused<<<dim3(nblk), dim3(NTH), 0, stream>>>(hx, cx1, cx2, dt, W, b, out);
}

// Round 3
// 548.004 us; speedup vs baseline: 1.8827x; 1.8827x over previous
//
#include <hip/hip_runtime.h>
#include <hip/hip_bf16.h>
#include <stdint.h>

// LSTMCell fused: g = hx @ W + b (M=8192,K=2048,N=7*2048) + gate math.
// R3: bf16 pre-conversion of W/hx into d_ws (tile-contiguous, XOR-swizzled
// layout) -> main GEMM stages via global_load_lds(16B), 16 waves/block,
// acc=56/lane (4 waves/SIMD), single-barrier double-buffer.
// Fallback (ws too small): R2 f32 kernel.

#define B_SZ 8192
#define D_SZ 2048
#define H_SZ 2048
#define NG   7
#define NW   (NG * H_SZ)          // 14336
#define BM   256
#define BN   32
#define BK   32
#define NKST (D_SZ / BK)          // 64
#define NBX  (B_SZ / BM)          // 32
#define NBY  (H_SZ / BN)          // 64

// bf16 tile images in ws:
//  W' : [by(64)][ks(64)] -> 224 rows x 32 k bf16 = 14336 B contiguous
//  hx': [bx(32)][ks(64)] -> 256 rows x 32 k bf16 = 16384 B contiguous
// Within a tile: row-major, 64 B/row, 16B chunk pc stores logical k-octet
// koct = pc ^ ((row>>1)&3)  (XOR swizzle baked in).
#define WB_BYTES   ((size_t)NBY * NKST * 14336)   // 58,720,256
#define HXB_OFF    WB_BYTES
#define HXB_BYTES  ((size_t)NBX * NKST * 16384)   // 33,554,432
#define WS_NEEDED  (WB_BYTES + HXB_BYTES)         // 92,274,688

typedef __attribute__((ext_vector_type(8))) short bf16x8;
typedef __attribute__((ext_vector_type(4))) float f32x4;

__device__ __forceinline__ uint32_t cvtpk(float lo, float hi) {
    uint32_t r;
    asm("v_cvt_pk_bf16_f32 %0, %1, %2" : "=v"(r) : "v"(lo), "v"(hi));
    return r;
}
__device__ __forceinline__ void glds16(const void* g, void* l) {
    __builtin_amdgcn_global_load_lds(
        (const __attribute__((address_space(1))) uint32_t*)g,
        (__attribute__((address_space(3))) uint32_t*)l, 16, 0, 0);
}
__device__ __forceinline__ float sigmoidf_(float x) {
    return 1.0f / (1.0f + __expf(-x));
}
__device__ __forceinline__ float tanhf_(float x) {
    float ax = fabsf(x);
    float e = __expf(2.0f * ax);
    float t = 1.0f - 2.0f / (e + 1.0f);
    return copysignf(t, x);
}
__device__ __forceinline__ float softplusf_(float x) {
    return (x > 30.0f) ? x : __logf(1.0f + __expf(x));
}

// ---------------- convert W -> W' (bf16, transposed, swizzled) -------------
__global__ __launch_bounds__(896) void conv_w(const float* __restrict__ W,
                                              char* __restrict__ wb)
{
    const int by = blockIdx.x >> 6;
    const int ks = blockIdx.x & 63;
    const int u  = threadIdx.x;          // 0..895 = 224 rows x 4 chunks
    const int r  = u >> 2;               // row: g*32+n
    const int pc = u & 3;
    const int koct = pc ^ ((r >> 1) & 3);
    const int g  = r >> 5;
    const int n  = r & 31;
    const int col = g * H_SZ + by * BN + n;
    const float* src = W + (size_t)(ks * BK + koct * 8) * NW + col;
    float w0 = src[0];
    float w1 = src[(size_t)NW];
    float w2 = src[(size_t)2 * NW];
    float w3 = src[(size_t)3 * NW];
    float w4 = src[(size_t)4 * NW];
    float w5 = src[(size_t)5 * NW];
    float w6 = src[(size_t)6 * NW];
    float w7 = src[(size_t)7 * NW];
    uint4 o;
    o.x = cvtpk(w0, w1); o.y = cvtpk(w2, w3);
    o.z = cvtpk(w4, w5); o.w = cvtpk(w6, w7);
    *(uint4*)(wb + (size_t)blockIdx.x * 14336 + u * 16) = o;
}

// ---------------- convert hx -> hx' (bf16, swizzled) -----------------------
__global__ __launch_bounds__(1024) void conv_hx(const float* __restrict__ hx,
                                                char* __restrict__ hxb)
{
    const int bx = blockIdx.x >> 6;
    const int ks = blockIdx.x & 63;
    const int u  = threadIdx.x;          // 0..1023 = 256 rows x 4 chunks
    const int r  = u >> 2;
    const int pc = u & 3;
    const int koct = pc ^ ((r >> 1) & 3);
    const float* src = hx + (size_t)(bx * BM + r) * D_SZ + ks * BK + koct * 8;
    f32x4 a = *(const f32x4*)(src);
    f32x4 b = *(const f32x4*)(src + 4);
    uint4 o;
    o.x = cvtpk(a[0], a[1]); o.y = cvtpk(a[2], a[3]);
    o.z = cvtpk(b[0], b[1]); o.w = cvtpk(b[2], b[3]);
    *(uint4*)(hxb + (size_t)blockIdx.x * 16384 + u * 16) = o;
}

// ---------------- main bf16 kernel -----------------------------------------
#define NTH3 1024
__global__ __launch_bounds__(NTH3, 4) void lstm_bf16(
    const char* __restrict__ wb, const char* __restrict__ hxb,
    const float* __restrict__ cx1, const float* __restrict__ cx2,
    const float* __restrict__ dt, const float* __restrict__ bias,
    float* __restrict__ out)
{
    // smem: A0 A1 (16384 each) | B0 B1 (14336 each) = 61440 B
    __shared__ char smem[2 * 16384 + 2 * 14336];

    const int tid  = threadIdx.x;
    const int lane = tid & 63;
    const int wid  = tid >> 6;           // 0..15
    const int wm   = wid >> 1;           // 0..7
    const int wn   = wid & 1;            // 0..1
    const int l15  = lane & 15;
    const int lg   = lane >> 4;

    // block order: XCD chunk, then by-pairs (W panel 2x stays L2-hot)
    const int b0  = blockIdx.x;
    const int swz = (b0 & 7) * 256 + (b0 >> 3);
    const int by2 = swz >> 6;            // 0..31
    const int rem = swz & 63;
    const int bx  = rem >> 1;            // 0..31
    const int by  = by2 * 2 + (rem & 1); // 0..63
    const int gm0 = bx * BM;
    const int n0  = by * BN;

    const size_t hx_tile0 = (size_t)(bx * NKST) << 14;       // *16384
    const size_t w_tile0  = (size_t)(by * NKST) * 14336;

    // fragment read offsets (ushort idx), XOR chunk = lg ^ ((l15>>1)&3)
    const int xch  = (lg ^ ((l15 >> 1) & 3)) * 8;
    const int aoff0 = (wm * 32 + l15) * 32 + xch;
    const int aoff1 = aoff0 + 16 * 32;
    int boff[NG];
    #pragma unroll
    for (int g = 0; g < NG; ++g)
        boff[g] = (g * 32 + wn * 16 + l15) * 32 + xch;

    f32x4 acc[NG][2];
    #pragma unroll
    for (int g = 0; g < NG; ++g) {
        acc[g][0] = (f32x4){0.f, 0.f, 0.f, 0.f};
        acc[g][1] = (f32x4){0.f, 0.f, 0.f, 0.f};
    }

    const int lane16 = lane << 4;

    auto stage = [&](int c, int k) {
        // A: 16 parts of 1KB; wave wid -> part wid
        {
            const char* src = hxb + hx_tile0 + ((size_t)k << 14) + (wid << 10) + lane16;
            glds16(src, smem + c * 16384 + (wid << 10));
        }
        // B: 14 parts of 1KB; waves 0..13
        if (wid < 14) {
            const char* src = wb + w_tile0 + (size_t)k * 14336 + (wid << 10) + lane16;
            glds16(src, smem + 2 * 16384 + c * 14336 + (wid << 10));
        }
    };

    auto compute = [&](int c) {
        const ushort* sa = (const ushort*)(smem + c * 16384);
        const ushort* sb = (const ushort*)(smem + 2 * 16384 + c * 14336);
        bf16x8 af0 = *(const bf16x8*)(sa + aoff0);
        bf16x8 af1 = *(const bf16x8*)(sa + aoff1);
        #pragma unroll
        for (int g = 0; g < NG; ++g) {
            bf16x8 bfr = *(const bf16x8*)(sb + boff[g]);
            acc[g][0] = __builtin_amdgcn_mfma_f32_16x16x32_bf16(af0, bfr, acc[g][0], 0, 0, 0);
            acc[g][1] = __builtin_amdgcn_mfma_f32_16x16x32_bf16(af1, bfr, acc[g][1], 0, 0, 0);
        }
    };

    stage(0, 0);
    __syncthreads();
    for (int k = 0; k < NKST; k += 2) {
        stage(1, k + 1);                   // k+1 <= 63 always
        compute(0);
        __syncthreads();
        if (k + 2 < NKST) stage(0, k + 2);
        compute(1);
        __syncthreads();
    }

    // epilogue
    const size_t BH = (size_t)B_SZ * H_SZ;
    const int j = n0 + wn * 16 + l15;
    float bj[NG];
    #pragma unroll
    for (int g = 0; g < NG; ++g) bj[g] = bias[g * H_SZ + j];

    #pragma unroll
    for (int mf = 0; mf < 2; ++mf) {
        #pragma unroll
        for (int r = 0; r < 4; ++r) {
            int row = gm0 + wm * 32 + mf * 16 + lg * 4 + r;
            float dtv = dt[row];
            float i1 = sigmoidf_(acc[0][mf][r] + bj[0]);
            float i2 = sigmoidf_(acc[1][mf][r] + bj[1]);
            float f1 = sigmoidf_(acc[2][mf][r] + bj[2]);
            float f2 = sigmoidf_(acc[3][mf][r] + bj[3]);
            float o  = sigmoidf_(acc[4][mf][r] + bj[4]);
            float z  = tanhf_(acc[5][mf][r] + bj[5]);
            float dec = softplusf_(acc[6][mf][r] + bj[6]);
            size_t idx = (size_t)row * H_SZ + j;
            float c1 = cx1[idx], c2 = cx2[idx];
            float cy1 = f1 * c1 + i1 * z;
            float cy2 = f2 * c2 + i2 * z;
            float ct  = cy2 + (cy1 - cy2) * __expf(-dec * dtv);
            float ht  = o * tanhf_(ct);
            out[idx]          = cy1;
            out[BH + idx]     = cy2;
            out[2 * BH + idx] = ht;
        }
    }
}

// ---------------- f32 fallback (R2, passed) --------------------------------
#define NTH  512
#define LDP  40
__global__ __launch_bounds__(NTH, 2) void lstm_f32(
    const float* __restrict__ hx, const float* __restrict__ cx1,
    const float* __restrict__ cx2, const float* __restrict__ dt,
    const float* __restrict__ W, const float* __restrict__ bias,
    float* __restrict__ out)
{
    __shared__ ushort sA[BM * LDP];
    __shared__ ushort sB[NG * BN * LDP];

    const int tid = threadIdx.x;
    const int nwg = gridDim.x;
    const int cpx = nwg >> 3;
    const int b0  = blockIdx.x;
    const int swz = (b0 & 7) * cpx + (b0 >> 3);
    const int bx  = swz & 31;
    const int by  = swz >> 5;
    const int gm0 = bx * BM;
    const int n0  = by * BN;

    const int lane = tid & 63;
    const int wid  = tid >> 6;
    const int wm   = wid >> 1;
    const int wn   = wid & 1;
    const int l15  = lane & 15;
    const int lg   = lane >> 4;

    const int ar0 = tid >> 2,          aq0 = tid & 3;
    const int ar1 = (tid + 512) >> 2,  aq1 = tid & 3;
    const bool hasB = (tid < 448);
    const int bg  = tid >> 6;
    const int bkq = (tid >> 3) & 7;
    const int bnq = tid & 7;

    f32x4 pa[4];
    f32x4 pb[4];

    auto issue_loads = [&](int K0) {
        {
            const float* p = hx + (size_t)(gm0 + ar0) * D_SZ + K0 + aq0 * 8;
            pa[0] = *(const f32x4*)(p);
            pa[1] = *(const f32x4*)(p + 4);
        }
        {
            const float* p = hx + (size_t)(gm0 + ar1) * D_SZ + K0 + aq1 * 8;
            pa[2] = *(const f32x4*)(p);
            pa[3] = *(const f32x4*)(p + 4);
        }
        if (hasB) {
            const float* p = W + (size_t)(K0 + bkq * 4) * NW + bg * H_SZ + n0 + bnq * 4;
            pb[0] = *(const f32x4*)(p);
            pb[1] = *(const f32x4*)(p + NW);
            pb[2] = *(const f32x4*)(p + 2 * NW);
            pb[3] = *(const f32x4*)(p + 3 * NW);
        }
    };

    auto store_lds = [&]() {
        {
            uint4 u;
            u.x = cvtpk(pa[0][0], pa[0][1]); u.y = cvtpk(pa[0][2], pa[0][3]);
            u.z = cvtpk(pa[1][0], pa[1][1]); u.w = cvtpk(pa[1][2], pa[1][3]);
            *(uint4*)(&sA[ar0 * LDP + aq0 * 8]) = u;
        }
        {
            uint4 u;
            u.x = cvtpk(pa[2][0], pa[2][1]); u.y = cvtpk(pa[2][2], pa[2][3]);
            u.z = cvtpk(pa[3][0], pa[3][1]); u.w = cvtpk(pa[3][2], pa[3][3]);
            *(uint4*)(&sA[ar1 * LDP + aq1 * 8]) = u;
        }
        if (hasB) {
            #pragma unroll
            for (int jj = 0; jj < 4; ++jj) {
                uint2 v;
                v.x = cvtpk(pb[0][jj], pb[1][jj]);
                v.y = cvtpk(pb[2][jj], pb[3][jj]);
                *(uint2*)(&sB[(bg * BN + bnq * 4 + jj) * LDP + bkq * 4]) = v;
            }
        }
    };

    f32x4 acc[NG][4];
    #pragma unroll
    for (int g = 0; g < NG; ++g)
        #pragma unroll
        for (int mf = 0; mf < 4; ++mf)
            acc[g][mf] = (f32x4){0.f, 0.f, 0.f, 0.f};

    int aoff[4];
    #pragma unroll
    for (int mf = 0; mf < 4; ++mf)
        aoff[mf] = (wm * 64 + mf * 16 + l15) * LDP + lg * 8;
    int boff[NG];
    #pragma unroll
    for (int g = 0; g < NG; ++g)
        boff[g] = (g * BN + wn * 16 + l15) * LDP + lg * 8;

    issue_loads(0);
    for (int kk = 0; kk < NKST; ++kk) {
        store_lds();
        __syncthreads();
        if (kk + 1 < NKST) issue_loads((kk + 1) * BK);

        bf16x8 af[4];
        #pragma unroll
        for (int mf = 0; mf < 4; ++mf)
            af[mf] = *(const bf16x8*)(&sA[aoff[mf]]);
        #pragma unroll
        for (int g = 0; g < NG; ++g) {
            bf16x8 bfr = *(const bf16x8*)(&sB[boff[g]]);
            #pragma unroll
            for (int mf = 0; mf < 4; ++mf)
                acc[g][mf] = __builtin_amdgcn_mfma_f32_16x16x32_bf16(
                    af[mf], bfr, acc[g][mf], 0, 0, 0);
        }
        __syncthreads();
    }

    const size_t BH = (size_t)B_SZ * H_SZ;
    const int j = n0 + wn * 16 + l15;
    float bj[NG];
    #pragma unroll
    for (int g = 0; g < NG; ++g) bj[g] = bias[g * H_SZ + j];

    #pragma unroll
    for (int mf = 0; mf < 4; ++mf) {
        #pragma unroll
        for (int r = 0; r < 4; ++r) {
            int row = gm0 + wm * 64 + mf * 16 + lg * 4 + r;
            float dtv = dt[row];
            float i1 = sigmoidf_(acc[0][mf][r] + bj[0]);
            float i2 = sigmoidf_(acc[1][mf][r] + bj[1]);
            float f1 = sigmoidf_(acc[2][mf][r] + bj[2]);
            float f2 = sigmoidf_(acc[3][mf][r] + bj[3]);
            float o  = sigmoidf_(acc[4][mf][r] + bj[4]);
            float z  = tanhf_(acc[5][mf][r] + bj[5]);
            float dec = softplusf_(acc[6][mf][r] + bj[6]);
            size_t idx = (size_t)row * H_SZ + j;
            float c1 = cx1[idx], c2 = cx2[idx];
            float cy1 = f1 * c1 + i1 * z;
            float cy2 = f2 * c2 + i2 * z;
            float ct  = cy2 + (cy1 - cy2) * __expf(-dec * dtv);
            float ht  = o * tanhf_(ct);
            out[idx]          = cy1;
            out[BH + idx]     = cy2;
            out[2 * BH + idx] = ht;
        }
    }
}

extern "C" void kernel_launch(void* const* d_in, const int* in_sizes, int n_in,
                              void* d_out, int out_size, void* d_ws, size_t ws_size,
                              hipStream_t stream) {
    const float* hx  = (const float*)d_in[0];
    const float* cx1 = (const float*)d_in[1];
    const float* cx2 = (const float*)d_in[2];
    const float* dt  = (const float*)d_in[4];
    const float* W   = (const float*)d_in[5];
    const float* b   = (const float*)d_in[6];
    float* out = (float*)d_out;

    if (ws_size >= WS_NEEDED) {
        char* wb  = (char*)d_ws;
        char* hxb = (char*)d_ws + HXB_OFF;
        conv_w<<<dim3(NBY * NKST), dim3(896), 0, stream>>>(W, wb);
        conv_hx<<<dim3(NBX * NKST), dim3(1024), 0, stream>>>(hx, hxb);
        lstm_bf16<<<dim3(NBX * NBY), dim3(NTH3), 0, stream>>>(
            wb, hxb, cx1, cx2, dt, b, out);
    } else {
        lstm_f32<<<dim3(NBX * NBY), dim3(NTH), 0, stream>>>(
            hx, cx1, cx2, dt, W, b, out);
    }
}

// Round 4
// 543.881 us; speedup vs baseline: 1.8970x; 1.0076x over previous
//
#include <hip/hip_runtime.h>
#include <hip/hip_bf16.h>
#include <stdint.h>

// LSTMCell fused: g = hx @ W + b (M=8192,K=2048,N=7*2048) + gate math.
// R4: depth-3 counted-vmcnt software pipeline (T3/T4): 4 LDS buffers,
// s_waitcnt vmcnt(4) + raw s_barrier per K-step (never drain to 0 in loop).
// Staging via global_load_lds(16B) from bf16 pre-converted ws images.

#define B_SZ 8192
#define D_SZ 2048
#define H_SZ 2048
#define NG   7
#define NW   (NG * H_SZ)          // 14336
#define BM   256
#define BN   32
#define BK   32
#define NKST (D_SZ / BK)          // 64
#define NBX  (B_SZ / BM)          // 32
#define NBY  (H_SZ / BN)          // 64

// bf16 tile images in ws (R3 layout, unchanged):
//  W' : [by(64)][ks(64)] -> 224 rows x 32 k bf16 = 14336 B contiguous
//  hx': [bx(32)][ks(64)] -> 256 rows x 32 k bf16 = 16384 B contiguous
// Within a tile: row-major, 64 B/row, 16B chunk pc stores logical k-octet
// koct = pc ^ ((row>>1)&3)  (XOR swizzle baked in).
#define WB_BYTES   ((size_t)NBY * NKST * 14336)   // 58,720,256
#define HXB_OFF    WB_BYTES
#define HXB_BYTES  ((size_t)NBX * NKST * 16384)   // 33,554,432
#define WS_NEEDED  (WB_BYTES + HXB_BYTES)         // 92,274,688

typedef __attribute__((ext_vector_type(8))) short bf16x8;
typedef __attribute__((ext_vector_type(4))) float f32x4;

__device__ __forceinline__ uint32_t cvtpk(float lo, float hi) {
    uint32_t r;
    asm("v_cvt_pk_bf16_f32 %0, %1, %2" : "=v"(r) : "v"(lo), "v"(hi));
    return r;
}
__device__ __forceinline__ void glds16(const void* g, void* l) {
    __builtin_amdgcn_global_load_lds(
        (const __attribute__((address_space(1))) uint32_t*)g,
        (__attribute__((address_space(3))) uint32_t*)l, 16, 0, 0);
}
__device__ __forceinline__ float sigmoidf_(float x) {
    return 1.0f / (1.0f + __expf(-x));
}
__device__ __forceinline__ float tanhf_(float x) {
    float ax = fabsf(x);
    float e = __expf(2.0f * ax);
    float t = 1.0f - 2.0f / (e + 1.0f);
    return copysignf(t, x);
}
__device__ __forceinline__ float softplusf_(float x) {
    return (x > 30.0f) ? x : __logf(1.0f + __expf(x));
}

// ---------------- convert W -> W' (bf16, transposed, swizzled) -------------
__global__ __launch_bounds__(896) void conv_w(const float* __restrict__ W,
                                              char* __restrict__ wb)
{
    const int by = blockIdx.x >> 6;
    const int ks = blockIdx.x & 63;
    const int u  = threadIdx.x;          // 0..895 = 224 rows x 4 chunks
    const int r  = u >> 2;               // row: g*32+n
    const int pc = u & 3;
    const int koct = pc ^ ((r >> 1) & 3);
    const int g  = r >> 5;
    const int n  = r & 31;
    const int col = g * H_SZ + by * BN + n;
    const float* src = W + (size_t)(ks * BK + koct * 8) * NW + col;
    float w0 = src[0];
    float w1 = src[(size_t)NW];
    float w2 = src[(size_t)2 * NW];
    float w3 = src[(size_t)3 * NW];
    float w4 = src[(size_t)4 * NW];
    float w5 = src[(size_t)5 * NW];
    float w6 = src[(size_t)6 * NW];
    float w7 = src[(size_t)7 * NW];
    uint4 o;
    o.x = cvtpk(w0, w1); o.y = cvtpk(w2, w3);
    o.z = cvtpk(w4, w5); o.w = cvtpk(w6, w7);
    *(uint4*)(wb + (size_t)blockIdx.x * 14336 + u * 16) = o;
}

// ---------------- convert hx -> hx' (bf16, swizzled) -----------------------
__global__ __launch_bounds__(1024) void conv_hx(const float* __restrict__ hx,
                                                char* __restrict__ hxb)
{
    const int bx = blockIdx.x >> 6;
    const int ks = blockIdx.x & 63;
    const int u  = threadIdx.x;          // 0..1023 = 256 rows x 4 chunks
    const int r  = u >> 2;
    const int pc = u & 3;
    const int koct = pc ^ ((r >> 1) & 3);
    const float* src = hx + (size_t)(bx * BM + r) * D_SZ + ks * BK + koct * 8;
    f32x4 a = *(const f32x4*)(src);
    f32x4 b = *(const f32x4*)(src + 4);
    uint4 o;
    o.x = cvtpk(a[0], a[1]); o.y = cvtpk(a[2], a[3]);
    o.z = cvtpk(b[0], b[1]); o.w = cvtpk(b[2], b[3]);
    *(uint4*)(hxb + (size_t)blockIdx.x * 16384 + u * 16) = o;
}

// ---------------- main bf16 kernel -----------------------------------------
#define NTH3 1024
#define BUFB 30720                     // 16384 (A) + 14336 (B)
#define NBUF 4

#define PIPE_WAIT(N)                                        \
    asm volatile("s_waitcnt vmcnt(" #N ")" ::: "memory");   \
    __builtin_amdgcn_s_barrier();                           \
    asm volatile("" ::: "memory");

__global__ __launch_bounds__(NTH3, 4) void lstm_bf16(
    const char* __restrict__ wb, const char* __restrict__ hxb,
    const float* __restrict__ cx1, const float* __restrict__ cx2,
    const float* __restrict__ dt, const float* __restrict__ bias,
    float* __restrict__ out)
{
    __shared__ char smem[NBUF * BUFB];   // 122880 B

    const int tid  = threadIdx.x;
    const int lane = tid & 63;
    const int wid  = tid >> 6;           // 0..15
    const int wm   = wid >> 1;           // 0..7
    const int wn   = wid & 1;            // 0..1
    const int l15  = lane & 15;
    const int lg   = lane >> 4;

    // block order: XCD chunk, then by-pairs (W panel 2x stays L2-hot)
    const int b0  = blockIdx.x;
    const int swz = (b0 & 7) * 256 + (b0 >> 3);
    const int by2 = swz >> 6;            // 0..31
    const int rem = swz & 63;
    const int bx  = rem >> 1;            // 0..31
    const int by  = by2 * 2 + (rem & 1); // 0..63
    const int gm0 = bx * BM;
    const int n0  = by * BN;

    const size_t hx_tile0 = (size_t)(bx * NKST) << 14;       // *16384
    const size_t w_tile0  = (size_t)(by * NKST) * 14336;

    // fragment read offsets (ushort idx), XOR chunk = lg ^ ((l15>>1)&3)
    const int xch  = (lg ^ ((l15 >> 1) & 3)) * 8;
    const int aoff0 = (wm * 32 + l15) * 32 + xch;
    const int aoff1 = aoff0 + 16 * 32;
    int boff[NG];
    #pragma unroll
    for (int g = 0; g < NG; ++g)
        boff[g] = (g * 32 + wn * 16 + l15) * 32 + xch;

    f32x4 acc[NG][2];
    #pragma unroll
    for (int g = 0; g < NG; ++g) {
        acc[g][0] = (f32x4){0.f, 0.f, 0.f, 0.f};
        acc[g][1] = (f32x4){0.f, 0.f, 0.f, 0.f};
    }

    const int lane16 = lane << 4;

    // Every wave issues EXACTLY 2 glds16 per stage (uniform vmcnt):
    //   A: 16 segs x 1024B (all lanes); B: 16 segs x 896B (lanes 0..55).
    auto stage = [&](int c, int k) {
        {
            const char* src = hxb + hx_tile0 + ((size_t)k << 14) + (wid << 10) + lane16;
            glds16(src, smem + c * BUFB + (wid << 10));
        }
        if (lane < 56) {
            const char* src = wb + w_tile0 + (size_t)k * 14336 + wid * 896 + lane16;
            glds16(src, smem + c * BUFB + 16384 + wid * 896);
        }
    };

    auto compute = [&](int c) {
        const ushort* sa = (const ushort*)(smem + c * BUFB);
        const ushort* sb = (const ushort*)(smem + c * BUFB + 16384);
        bf16x8 af0 = *(const bf16x8*)(sa + aoff0);
        bf16x8 af1 = *(const bf16x8*)(sa + aoff1);
        #pragma unroll
        for (int g = 0; g < NG; ++g) {
            bf16x8 bfr = *(const bf16x8*)(sb + boff[g]);
            acc[g][0] = __builtin_amdgcn_mfma_f32_16x16x32_bf16(af0, bfr, acc[g][0], 0, 0, 0);
            acc[g][1] = __builtin_amdgcn_mfma_f32_16x16x32_bf16(af1, bfr, acc[g][1], 0, 0, 0);
        }
    };

    // prologue: tiles 0..2 in flight (6 loads/wave outstanding)
    stage(0, 0);
    stage(1, 1);
    stage(2, 2);

    // steady state: before iter-t wait, outstanding = {t, t+1, t+2} (6).
    // vmcnt(4) drains tile t; stage(t+3) refills. Single barrier per step:
    // stage(t+3) writes buf[(t-1)&3], safe because barrier t guarantees all
    // waves finished compute(t-1).
    for (int t = 0; t < NKST - 3; ++t) {
        PIPE_WAIT(4)
        stage((t + 3) & 3, t + 3);
        compute(t & 3);
    }
    PIPE_WAIT(4)
    compute((NKST - 3) & 3);
    PIPE_WAIT(2)
    compute((NKST - 2) & 3);
    PIPE_WAIT(0)
    compute((NKST - 1) & 3);

    // epilogue
    const size_t BH = (size_t)B_SZ * H_SZ;
    const int j = n0 + wn * 16 + l15;
    float bj[NG];
    #pragma unroll
    for (int g = 0; g < NG; ++g) bj[g] = bias[g * H_SZ + j];

    #pragma unroll
    for (int mf = 0; mf < 2; ++mf) {
        #pragma unroll
        for (int r = 0; r < 4; ++r) {
            int row = gm0 + wm * 32 + mf * 16 + lg * 4 + r;
            float dtv = dt[row];
            float i1 = sigmoidf_(acc[0][mf][r] + bj[0]);
            float i2 = sigmoidf_(acc[1][mf][r] + bj[1]);
            float f1 = sigmoidf_(acc[2][mf][r] + bj[2]);
            float f2 = sigmoidf_(acc[3][mf][r] + bj[3]);
            float o  = sigmoidf_(acc[4][mf][r] + bj[4]);
            float z  = tanhf_(acc[5][mf][r] + bj[5]);
            float dec = softplusf_(acc[6][mf][r] + bj[6]);
            size_t idx = (size_t)row * H_SZ + j;
            float c1 = cx1[idx], c2 = cx2[idx];
            float cy1 = f1 * c1 + i1 * z;
            float cy2 = f2 * c2 + i2 * z;
            float ct  = cy2 + (cy1 - cy2) * __expf(-dec * dtv);
            float ht  = o * tanhf_(ct);
            out[idx]          = cy1;
            out[BH + idx]     = cy2;
            out[2 * BH + idx] = ht;
        }
    }
}

// ---------------- f32 fallback (R2, passed) --------------------------------
#define NTH  512
#define LDP  40
__global__ __launch_bounds__(NTH, 2) void lstm_f32(
    const float* __restrict__ hx, const float* __restrict__ cx1,
    const float* __restrict__ cx2, const float* __restrict__ dt,
    const float* __restrict__ W, const float* __restrict__ bias,
    float* __restrict__ out)
{
    __shared__ ushort sA[BM * LDP];
    __shared__ ushort sB[NG * BN * LDP];

    const int tid = threadIdx.x;
    const int nwg = gridDim.x;
    const int cpx = nwg >> 3;
    const int b0  = blockIdx.x;
    const int swz = (b0 & 7) * cpx + (b0 >> 3);
    const int bx  = swz & 31;
    const int by  = swz >> 5;
    const int gm0 = bx * BM;
    const int n0  = by * BN;

    const int lane = tid & 63;
    const int wid  = tid >> 6;
    const int wm   = wid >> 1;
    const int wn   = wid & 1;
    const int l15  = lane & 15;
    const int lg   = lane >> 4;

    const int ar0 = tid >> 2,          aq0 = tid & 3;
    const int ar1 = (tid + 512) >> 2,  aq1 = tid & 3;
    const bool hasB = (tid < 448);
    const int bg  = tid >> 6;
    const int bkq = (tid >> 3) & 7;
    const int bnq = tid & 7;

    f32x4 pa[4];
    f32x4 pb[4];

    auto issue_loads = [&](int K0) {
        {
            const float* p = hx + (size_t)(gm0 + ar0) * D_SZ + K0 + aq0 * 8;
            pa[0] = *(const f32x4*)(p);
            pa[1] = *(const f32x4*)(p + 4);
        }
        {
            const float* p = hx + (size_t)(gm0 + ar1) * D_SZ + K0 + aq1 * 8;
            pa[2] = *(const f32x4*)(p);
            pa[3] = *(const f32x4*)(p + 4);
        }
        if (hasB) {
            const float* p = W + (size_t)(K0 + bkq * 4) * NW + bg * H_SZ + n0 + bnq * 4;
            pb[0] = *(const f32x4*)(p);
            pb[1] = *(const f32x4*)(p + NW);
            pb[2] = *(const f32x4*)(p + 2 * NW);
            pb[3] = *(const f32x4*)(p + 3 * NW);
        }
    };

    auto store_lds = [&]() {
        {
            uint4 u;
            u.x = cvtpk(pa[0][0], pa[0][1]); u.y = cvtpk(pa[0][2], pa[0][3]);
            u.z = cvtpk(pa[1][0], pa[1][1]); u.w = cvtpk(pa[1][2], pa[1][3]);
            *(uint4*)(&sA[ar0 * LDP + aq0 * 8]) = u;
        }
        {
            uint4 u;
            u.x = cvtpk(pa[2][0], pa[2][1]); u.y = cvtpk(pa[2][2], pa[2][3]);
            u.z = cvtpk(pa[3][0], pa[3][1]); u.w = cvtpk(pa[3][2], pa[3][3]);
            *(uint4*)(&sA[ar1 * LDP + aq1 * 8]) = u;
        }
        if (hasB) {
            #pragma unroll
            for (int jj = 0; jj < 4; ++jj) {
                uint2 v;
                v.x = cvtpk(pb[0][jj], pb[1][jj]);
                v.y = cvtpk(pb[2][jj], pb[3][jj]);
                *(uint2*)(&sB[(bg * BN + bnq * 4 + jj) * LDP + bkq * 4]) = v;
            }
        }
    };

    f32x4 acc[NG][4];
    #pragma unroll
    for (int g = 0; g < NG; ++g)
        #pragma unroll
        for (int mf = 0; mf < 4; ++mf)
            acc[g][mf] = (f32x4){0.f, 0.f, 0.f, 0.f};

    int aoff[4];
    #pragma unroll
    for (int mf = 0; mf < 4; ++mf)
        aoff[mf] = (wm * 64 + mf * 16 + l15) * LDP + lg * 8;
    int boff[NG];
    #pragma unroll
    for (int g = 0; g < NG; ++g)
        boff[g] = (g * BN + wn * 16 + l15) * LDP + lg * 8;

    issue_loads(0);
    for (int kk = 0; kk < NKST; ++kk) {
        store_lds();
        __syncthreads();
        if (kk + 1 < NKST) issue_loads((kk + 1) * BK);

        bf16x8 af[4];
        #pragma unroll
        for (int mf = 0; mf < 4; ++mf)
            af[mf] = *(const bf16x8*)(&sA[aoff[mf]]);
        #pragma unroll
        for (int g = 0; g < NG; ++g) {
            bf16x8 bfr = *(const bf16x8*)(&sB[boff[g]]);
            #pragma unroll
            for (int mf = 0; mf < 4; ++mf)
                acc[g][mf] = __builtin_amdgcn_mfma_f32_16x16x32_bf16(
                    af[mf], bfr, acc[g][mf], 0, 0, 0);
        }
        __syncthreads();
    }

    const size_t BH = (size_t)B_SZ * H_SZ;
    const int j = n0 + wn * 16 + l15;
    float bj[NG];
    #pragma unroll
    for (int g = 0; g < NG; ++g) bj[g] = bias[g * H_SZ + j];

    #pragma unroll
    for (int mf = 0; mf < 4; ++mf) {
        #pragma unroll
        for (int r = 0; r < 4; ++r) {
            int row = gm0 + wm * 64 + mf * 16 + lg * 4 + r;
            float dtv = dt[row];
            float i1 = sigmoidf_(acc[0][mf][r] + bj[0]);
            float i2 = sigmoidf_(acc[1][mf][r] + bj[1]);
            float f1 = sigmoidf_(acc[2][mf][r] + bj[2]);
            float f2 = sigmoidf_(acc[3][mf][r] + bj[3]);
            float o  = sigmoidf_(acc[4][mf][r] + bj[4]);
            float z  = tanhf_(acc[5][mf][r] + bj[5]);
            float dec = softplusf_(acc[6][mf][r] + bj[6]);
            size_t idx = (size_t)row * H_SZ + j;
            float c1 = cx1[idx], c2 = cx2[idx];
            float cy1 = f1 * c1 + i1 * z;
            float cy2 = f2 * c2 + i2 * z;
            float ct  = cy2 + (cy1 - cy2) * __expf(-dec * dtv);
            float ht  = o * tanhf_(ct);
            out[idx]          = cy1;
            out[BH + idx]     = cy2;
            out[2 * BH + idx] = ht;
        }
    }
}

extern "C" void kernel_launch(void* const* d_in, const int* in_sizes, int n_in,
                              void* d_out, int out_size, void* d_ws, size_t ws_size,
                              hipStream_t stream) {
    const float* hx  = (const float*)d_in[0];
    const float* cx1 = (const float*)d_in[1];
    const float* cx2 = (const float*)d_in[2];
    const float* dt  = (const float*)d_in[4];
    const float* W   = (const float*)d_in[5];
    const float* b   = (const float*)d_in[6];
    float* out = (float*)d_out;

    if (ws_size >= WS_NEEDED) {
        char* wb  = (char*)d_ws;
        char* hxb = (char*)d_ws + HXB_OFF;
        conv_w<<<dim3(NBY * NKST), dim3(896), 0, stream>>>(W, wb);
        conv_hx<<<dim3(NBX * NKST), dim3(1024), 0, stream>>>(hx, hxb);
        lstm_bf16<<<dim3(NBX * NBY), dim3(NTH3), 0, stream>>>(
            wb, hxb, cx1, cx2, dt, b, out);
    } else {
        lstm_f32<<<dim3(NBX * NBY), dim3(NTH), 0, stream>>>(
            hx, cx1, cx2, dt, W, b, out);
    }
}